// Round 5
// baseline (117.607 us; speedup 1.0000x reference)
//
#include <hip/hip_runtime.h>
#include <hip/hip_bf16.h>
#include <cstdint>
#include <cstddef>

#define Nn 8
#define Cc 128
#define Oo 128
#define Hh 64
#define Ww 64
#define LL (Hh * Ww)
#define KP 9

typedef __attribute__((ext_vector_type(8))) short short8;
typedef __attribute__((ext_vector_type(4))) float floatx4;
typedef __attribute__((ext_vector_type(4))) int intx4;

#define SGB(m, s, i) __builtin_amdgcn_sched_group_barrier(m, s, i)

__device__ __forceinline__ unsigned short f2bf(float f) {
  unsigned int u = __float_as_uint(f);
  u += 0x7fffu + ((u >> 16) & 1u);   // round-to-nearest-even
  return (unsigned short)(u >> 16);
}

// Fused prep:
//  blocks [0, 512):   x[n][c][h][w] fp32 -> xt[n][h][w][c] bf16
//  blocks [512, 896): w_b[o][c][3][3] fp32 -> wt2 fragment-contiguous bf16:
//    wt2[((b*9+kk)*4+c0)*4096 + ob1*2048 + wc*1024 + j*512 + ln15*32 + quad*8 + e]
//    so one wave's B fragment load = 1 KB fully contiguous.
__global__ __launch_bounds__(256) void prep_all(const float* __restrict__ x,
                                                const float* __restrict__ w0,
                                                const float* __restrict__ w1,
                                                const float* __restrict__ w2,
                                                unsigned short* __restrict__ xt,
                                                unsigned short* __restrict__ wt2) {
  __shared__ float tile[Cc][Ww + 1];
  __shared__ unsigned short wl[Cc * KP];
  const int bid = blockIdx.x;
  const int t = threadIdx.x;
  if (bid < Nn * Hh) {
    const int n = bid >> 6;
    const int h = bid & 63;
    const float* src = x + (size_t)n * Cc * LL + (size_t)h * Ww;
#pragma unroll
    for (int it = 0; it < 8; ++it) {
      const int idx = t + it * 256;          // 0..2047
      const int c = idx >> 4;
      const int w4 = (idx & 15) << 2;
      const float4 v = *reinterpret_cast<const float4*>(src + (size_t)c * LL + w4);
      tile[c][w4 + 0] = v.x; tile[c][w4 + 1] = v.y;
      tile[c][w4 + 2] = v.z; tile[c][w4 + 3] = v.w;
    }
    __syncthreads();
    unsigned short* dst = xt + (size_t)((n * Hh + h) * Ww) * Cc;
#pragma unroll
    for (int it = 0; it < 4; ++it) {
      const int idx = t + it * 256;          // 0..1023
      const int w = idx >> 4;
      const int ch = (idx & 15) << 3;
      short8 v;
#pragma unroll
      for (int q = 0; q < 8; ++q)
        ((unsigned short*)&v)[q] = f2bf(tile[ch + q][w]);
      *reinterpret_cast<short8*>(dst + (size_t)w * Cc + ch) = v;
    }
  } else {
    const int bo = bid - Nn * Hh;            // 0..383
    const int b = bo >> 7;
    const int o = bo & 127;
    const float* w = (b == 0) ? w0 : (b == 1) ? w1 : w2;
    const float* src = w + (size_t)o * Cc * KP;   // contiguous 1152 floats
#pragma unroll
    for (int it = 0; it < 5; ++it) {
      const int idx = t + it * 256;
      if (idx < Cc * KP) wl[idx] = f2bf(src[idx]);   // wl[c*9+kk]
    }
    __syncthreads();
    const int obase = ((o >> 6) & 1) * 2048 + ((o >> 5) & 1) * 1024 +
                      ((o >> 4) & 1) * 512 + (o & 15) * 32;
#pragma unroll
    for (int it = 0; it < 5; ++it) {
      const int idx = t + it * 256;          // 0..1151 = kk*128 + c
      if (idx < Cc * KP) {
        const int kk = idx >> 7;
        const int c = idx & 127;
        const int c0 = c >> 5;
        const int cc = c & 31;
        wt2[(size_t)(b * 36 + kk * 4 + c0) * 4096 + obase + cc] = wl[c * KP + kk];
      }
    }
  }
}

#define LDXC 132          // pixel stride 264 B = 66 words ≡ 2 mod 32 -> 2-way (free)
#define HALO_COLS 66      // w in [-1, 64]
#define HALO_ROWS 4       // h in [h0-1, h0+2]
#define NSTEP 36          // 9 kk x 4 c0-chunks
#define BSTRIDE 147456    // b * KP * 4 * 4096 shorts between branches

__global__ __launch_bounds__(256, 2) void conv_main(
    const unsigned short* __restrict__ xt,
    const unsigned short* __restrict__ wt2,
    const float* __restrict__ depth,
    const float* __restrict__ fx,
    float* __restrict__ out) {
  __shared__ unsigned short Xs[HALO_ROWS * HALO_COLS * LDXC];  // 69696 B
  __shared__ unsigned int code32[128];                         // 512 B

  const int g = blockIdx.x;          // 512 blocks
  const int n = g >> 6;
  const int rem = g & 63;
  const int pb = rem >> 1;           // 0..31  -> row pair
  const int ob1 = rem & 1;           // o-half
  const int h0 = pb * 2;

  const int tid = threadIdx.x;
  const int lane = tid & 63;
  const int wave = tid >> 6;
  const int ln15 = lane & 15;
  const int quad = lane >> 4;
  const int hsel = wave >> 1;        // pixel row within block (0/1)
  const int m_half = hsel * 64;
  const int wc = wave & 1;

  // fragment-contiguous B base for this wave
  const unsigned short* wfrag = wt2 + (size_t)(ob1 * 2048 + wc * 1024 + ln15 * 32 + quad * 8);

  short8 Bb[4][6];   // rotating 4-slot B prefetch (distance 3)
  short8 Aa[2][4];   // rotating 2-slot A prefetch (distance 1)

#define LOADB(S)                                                                  \
  if ((S) < NSTEP) {                                                              \
    const unsigned short* bp = wfrag + (size_t)(S) * 4096;                        \
    Bb[(S) & 3][0] = *reinterpret_cast<const short8*>(bp);                        \
    Bb[(S) & 3][1] = *reinterpret_cast<const short8*>(bp + 512);                  \
    Bb[(S) & 3][2] = *reinterpret_cast<const short8*>(bp + BSTRIDE);              \
    Bb[(S) & 3][3] = *reinterpret_cast<const short8*>(bp + BSTRIDE + 512);        \
    Bb[(S) & 3][4] = *reinterpret_cast<const short8*>(bp + 2 * BSTRIDE);          \
    Bb[(S) & 3][5] = *reinterpret_cast<const short8*>(bp + 2 * BSTRIDE + 512);    \
  }

#define LOADA(S)                                                                  \
  if ((S) < NSTEP) {                                                              \
    const int kkp = (S) >> 2, c0p = (S) & 3;                                      \
    const int dyp = kkp / 3, dxp = kkp % 3;                                       \
    const int ab = ((hsel + dyp) * HALO_COLS + ln15 + dxp) * LDXC + quad * 8 + c0p * 32; \
    Aa[(S) & 1][0] = *reinterpret_cast<const short8*>(&Xs[ab]);                   \
    Aa[(S) & 1][1] = *reinterpret_cast<const short8*>(&Xs[ab + 16 * LDXC]);       \
    Aa[(S) & 1][2] = *reinterpret_cast<const short8*>(&Xs[ab + 32 * LDXC]);       \
    Aa[(S) & 1][3] = *reinterpret_cast<const short8*>(&Xs[ab + 48 * LDXC]);       \
  }

  // ---- B prologue loads FIRST: L2 latency overlaps halo staging ----
  LOADB(0)
  LOADB(1)
  LOADB(2)

  // ---- stage halo tile ONCE: Xs[(hrel*66 + ww+1)][c] = xt[n, h0-1+hrel, ww, c] ----
#pragma unroll
  for (int it = 0; it < 17; ++it) {
    const int idx = tid + it * 256;          // chunks of 8 channels
    if (idx < HALO_ROWS * HALO_COLS * 16) {
      const int ch = (idx & 15) << 3;
      const int pixidx = idx >> 4;           // 0..263
      const int lc = pixidx % HALO_COLS;
      const int hrel = pixidx / HALO_COLS;
      const int hh = h0 - 1 + hrel;
      const int ww = lc - 1;
      short8 v = {0, 0, 0, 0, 0, 0, 0, 0};
      if (hh >= 0 && hh < Hh && ww >= 0 && ww < Ww)
        v = *reinterpret_cast<const short8*>(
            xt + (size_t)((n * Hh + hh) * Ww + ww) * Cc + ch);
      *reinterpret_cast<short8*>(&Xs[pixidx * LDXC + ch]) = v;
    }
  }

  // ---- depth masks ONCE: 27-bit code (3 bits per kk) per pixel ----
  if (tid < 128) {
    const int m = tid;
    const int h = h0 + (m >> 6);
    const int w = m & 63;
    const float center = depth[n * LL + h * Ww + w];
    const float fxv = fx[n];
    const float grid = center / fxv;     // PIXEL_SIZE*DILATION = 1
    const float half = 0.5f * grid;
    unsigned int packed = 0u;
#pragma unroll
    for (int kk = 0; kk < KP; ++kk) {
      const int hh = h + kk / 3 - 1;
      const int ww = w + kk % 3 - 1;
      float d = 0.0f;
      if (hh >= 0 && hh < Hh && ww >= 0 && ww < Ww) d = depth[n * LL + hh * Ww + ww];
      const float valid = (d != 0.0f && center != 0.0f) ? 1.0f : 0.0f;
      const float dm = d * valid;
      unsigned int cb = 0u;
      if (fabsf(dm - (center + grid)) <= half) cb |= 1u;
      float m1v = (fabsf(dm - center) <= half) ? 1.0f : 0.0f;
      m1v = m1v + 1.0f - valid;
      if (m1v > 1.0f) m1v = 1.0f;
      if (m1v > 0.5f) cb |= 2u;
      if (fabsf(dm - (center - grid)) <= half) cb |= 4u;
      packed |= cb << (3 * kk);
    }
    code32[m] = packed;
  }

  __syncthreads();   // the ONLY barrier

  unsigned int cd[4];
#pragma unroll
  for (int i = 0; i < 4; ++i) cd[i] = code32[m_half + i * 16 + ln15];

  const floatx4 zf4 = {0.f, 0.f, 0.f, 0.f};
  floatx4 acc[4][2];
#pragma unroll
  for (int i = 0; i < 4; ++i)
#pragma unroll
    for (int j = 0; j < 2; ++j) acc[i][j] = zf4;

  LOADA(0)

  // ---- fully unrolled 36-step pipeline, compile-time s everywhere ----
  // per step: prefetch B(s+3) [6 VMEM], A(s+1) [4 DS], compute 24 MFMA.
  // SGB template interleaves VMEM/DS 1:1-ish with MFMA (AITER pattern);
  // VALU left unconstrained so masks/addr thread through the gaps.
#pragma unroll
  for (int s = 0; s < NSTEP; ++s) {
    LOADB(s + 3)
    LOADA(s + 1)
    const int kk = s >> 2;
    const int shift = 3 * kk;
    const short8* B = Bb[s & 3];
    const short8* A = Aa[s & 1];
#pragma unroll
    for (int b = 0; b < 3; ++b) {
#pragma unroll
      for (int i = 0; i < 4; ++i) {
        const int msk = __builtin_amdgcn_sbfe((int)cd[i], shift + b, 1);
        intx4 a4 = *reinterpret_cast<const intx4*>(&A[i]);
        intx4 m4 = {msk, msk, msk, msk};
        a4 &= m4;
        const short8 af = *reinterpret_cast<const short8*>(&a4);
        acc[i][0] = __builtin_amdgcn_mfma_f32_16x16x32_bf16(af, B[b * 2 + 0], acc[i][0], 0, 0, 0);
        acc[i][1] = __builtin_amdgcn_mfma_f32_16x16x32_bf16(af, B[b * 2 + 1], acc[i][1], 0, 0, 0);
      }
    }
    SGB(0x020, 2, 0); SGB(0x008, 4, 0);
    SGB(0x100, 2, 0); SGB(0x008, 4, 0);
    SGB(0x020, 2, 0); SGB(0x008, 4, 0);
    SGB(0x100, 2, 0); SGB(0x008, 4, 0);
    SGB(0x020, 2, 0); SGB(0x008, 8, 0);
  }

  // ---- epilogue: D row = m (quad*4+reg), col = o (lane&15) ----
#pragma unroll
  for (int i = 0; i < 4; ++i) {
    const int m = m_half + i * 16 + quad * 4;
    const int h = h0 + (m >> 6);
    const int w = m & 63;
#pragma unroll
    for (int j = 0; j < 2; ++j) {
      const int o = ob1 * 64 + wc * 32 + j * 16 + ln15;
      float* dst = out + (size_t)(n * Oo + o) * LL + h * Ww + w;
      *reinterpret_cast<floatx4*>(dst) = acc[i][j];
    }
  }
}

extern "C" void kernel_launch(void* const* d_in, const int* in_sizes, int n_in,
                              void* d_out, int out_size, void* d_ws, size_t ws_size,
                              hipStream_t stream) {
  const float* x     = (const float*)d_in[0];
  const float* depth = (const float*)d_in[1];
  const float* fx    = (const float*)d_in[2];
  const float* w0    = (const float*)d_in[3];
  const float* w1    = (const float*)d_in[4];
  const float* w2    = (const float*)d_in[5];
  float* out = (float*)d_out;

  // ws layout: xt (8*64*64*128 bf16 = 8 MB) | wt2 (3*9*128*128 bf16 = 0.88 MB)
  unsigned short* xt = (unsigned short*)d_ws;
  unsigned short* wt2 = xt + (size_t)Nn * Hh * Ww * Cc;

  prep_all<<<Nn * Hh + 3 * Oo, 256, 0, stream>>>(x, w0, w1, w2, xt, wt2);
  conv_main<<<512, 256, 0, stream>>>(xt, wt2, depth, fx, out);
}

// Round 6
// 109.624 us; speedup vs baseline: 1.0728x; 1.0728x over previous
//
#include <hip/hip_runtime.h>
#include <hip/hip_bf16.h>
#include <cstdint>
#include <cstddef>

#define Nn 8
#define Cc 128
#define Oo 128
#define Hh 64
#define Ww 64
#define LL (Hh * Ww)
#define KP 9

typedef __attribute__((ext_vector_type(8))) short short8;
typedef __attribute__((ext_vector_type(4))) float floatx4;
typedef __attribute__((ext_vector_type(4))) int intx4;

#define SGB(m, s, i) __builtin_amdgcn_sched_group_barrier(m, s, i)

__device__ __forceinline__ unsigned short f2bf(float f) {
  unsigned int u = __float_as_uint(f);
  u += 0x7fffu + ((u >> 16) & 1u);   // round-to-nearest-even
  return (unsigned short)(u >> 16);
}

// Fused prep:
//  blocks [0, 512):    x[n][c][h][w] fp32 -> xt[n][h][w][c] bf16
//  blocks [512, 896):  w_b[o][c][3][3] fp32 -> wt2 fragment-contiguous bf16
//  blocks [896, 1024): depth -> packed 27-bit branch-mask codes per pixel
__global__ __launch_bounds__(256) void prep_all(const float* __restrict__ x,
                                                const float* __restrict__ w0,
                                                const float* __restrict__ w1,
                                                const float* __restrict__ w2,
                                                const float* __restrict__ depth,
                                                const float* __restrict__ fx,
                                                unsigned short* __restrict__ xt,
                                                unsigned short* __restrict__ wt2,
                                                unsigned int* __restrict__ codesg) {
  __shared__ float tile[Cc][Ww + 1];
  __shared__ unsigned short wl[Cc * KP];
  const int bid = blockIdx.x;
  const int t = threadIdx.x;
  if (bid < Nn * Hh) {
    const int n = bid >> 6;
    const int h = bid & 63;
    const float* src = x + (size_t)n * Cc * LL + (size_t)h * Ww;
#pragma unroll
    for (int it = 0; it < 8; ++it) {
      const int idx = t + it * 256;          // 0..2047
      const int c = idx >> 4;
      const int w4 = (idx & 15) << 2;
      const float4 v = *reinterpret_cast<const float4*>(src + (size_t)c * LL + w4);
      tile[c][w4 + 0] = v.x; tile[c][w4 + 1] = v.y;
      tile[c][w4 + 2] = v.z; tile[c][w4 + 3] = v.w;
    }
    __syncthreads();
    unsigned short* dst = xt + (size_t)((n * Hh + h) * Ww) * Cc;
#pragma unroll
    for (int it = 0; it < 4; ++it) {
      const int idx = t + it * 256;          // 0..1023
      const int w = idx >> 4;
      const int ch = (idx & 15) << 3;
      short8 v;
#pragma unroll
      for (int q = 0; q < 8; ++q)
        ((unsigned short*)&v)[q] = f2bf(tile[ch + q][w]);
      *reinterpret_cast<short8*>(dst + (size_t)w * Cc + ch) = v;
    }
  } else if (bid < Nn * Hh + 3 * Oo) {
    const int bo = bid - Nn * Hh;            // 0..383
    const int b = bo >> 7;
    const int o = bo & 127;
    const float* w = (b == 0) ? w0 : (b == 1) ? w1 : w2;
    const float* src = w + (size_t)o * Cc * KP;   // contiguous 1152 floats
#pragma unroll
    for (int it = 0; it < 5; ++it) {
      const int idx = t + it * 256;
      if (idx < Cc * KP) wl[idx] = f2bf(src[idx]);   // wl[c*9+kk]
    }
    __syncthreads();
    const int obase = ((o >> 6) & 1) * 2048 + ((o >> 5) & 1) * 1024 +
                      ((o >> 4) & 1) * 512 + (o & 15) * 32;
#pragma unroll
    for (int it = 0; it < 5; ++it) {
      const int idx = t + it * 256;          // 0..1151 = kk*128 + c
      if (idx < Cc * KP) {
        const int kk = idx >> 7;
        const int c = idx & 127;
        const int c0 = c >> 5;
        const int cc = c & 31;
        wt2[(size_t)(b * 36 + kk * 4 + c0) * 4096 + obase + cc] = wl[c * KP + kk];
      }
    }
  } else {
    const int p = (bid - (Nn * Hh + 3 * Oo)) * 256 + t;   // 0..32767
    const int n = p >> 12;
    const int rem = p & 4095;
    const int h = rem >> 6;
    const int w = rem & 63;
    const float center = depth[p];
    const float grid = center / fx[n];       // PIXEL_SIZE*DILATION = 1
    const float half = 0.5f * grid;
    unsigned int packed = 0u;
#pragma unroll
    for (int kk = 0; kk < KP; ++kk) {
      const int hh = h + kk / 3 - 1;
      const int ww = w + kk % 3 - 1;
      float d = 0.0f;
      if (hh >= 0 && hh < Hh && ww >= 0 && ww < Ww) d = depth[(n << 12) + hh * Ww + ww];
      const float valid = (d != 0.0f && center != 0.0f) ? 1.0f : 0.0f;
      const float dm = d * valid;
      unsigned int cb = 0u;
      if (fabsf(dm - (center + grid)) <= half) cb |= 1u;
      float m1v = (fabsf(dm - center) <= half) ? 1.0f : 0.0f;
      m1v = m1v + 1.0f - valid;
      if (m1v > 1.0f) m1v = 1.0f;
      if (m1v > 0.5f) cb |= 2u;
      if (fabsf(dm - (center - grid)) <= half) cb |= 4u;
      packed |= cb << (3 * kk);
    }
    codesg[p] = packed;
  }
}

#define LDXC 132          // pixel stride 264 B -> 2-way bank aliasing (free)
#define HALO_COLS 66      // w in [-1, 64]
#define HALO_ROWS 4       // h in [h0-1, h0+2]
#define NSTEP 18          // per wave: 9 kk x 2 local-c steps (split-K over c0 pairs)
#define BSTRIDE 147456    // shorts between branch weights in wt2

__global__ __launch_bounds__(256, 2) void conv_main(
    const unsigned short* __restrict__ xt,
    const unsigned short* __restrict__ wt2,
    const unsigned int* __restrict__ codesg,
    float* __restrict__ out) {
  __shared__ __align__(16) unsigned short Xs[HALO_ROWS * HALO_COLS * LDXC];  // 69696 B

  const int g = blockIdx.x;          // 512 blocks
  const int n = g >> 6;
  const int rem = g & 63;
  const int pb = rem >> 1;           // 0..31  -> row pair
  const int ob1 = rem & 1;           // o-half
  const int h0 = pb * 2;

  const int tid = threadIdx.x;
  const int lane = tid & 63;
  const int wave = tid >> 6;
  const int ln15 = lane & 15;
  const int quad = lane >> 4;
  const int wc = wave & 1;           // o 32-slice within the block's 64
  const int ks = wave >> 1;          // K-split: c0 pair {2ks, 2ks+1}

  // fragment-contiguous B base for this wave (ks shifts by 2 c0-chunks)
  const unsigned short* wfragk =
      wt2 + (size_t)(ob1 * 2048 + wc * 1024 + ln15 * 32 + quad * 8) + (size_t)ks * 8192;
  // LDS A base offset for this wave
  const int xbase = quad * 8 + ks * 64;

  short8 Bb[3][6];   // rotating 3-slot B prefetch (distance 2)
  short8 Aa[2][8];   // rotating 2-slot A prefetch (distance 1)

#define LOADB(SLOT, S)                                                            \
  {                                                                               \
    const unsigned short* bp = wfragk + (size_t)((((S) >> 1) * 4) + ((S) & 1)) * 4096; \
    Bb[SLOT][0] = *reinterpret_cast<const short8*>(bp);                           \
    Bb[SLOT][1] = *reinterpret_cast<const short8*>(bp + 512);                     \
    Bb[SLOT][2] = *reinterpret_cast<const short8*>(bp + BSTRIDE);                 \
    Bb[SLOT][3] = *reinterpret_cast<const short8*>(bp + BSTRIDE + 512);           \
    Bb[SLOT][4] = *reinterpret_cast<const short8*>(bp + 2 * BSTRIDE);             \
    Bb[SLOT][5] = *reinterpret_cast<const short8*>(bp + 2 * BSTRIDE + 512);       \
  }

#define LOADA(SLOT, S)                                                            \
  {                                                                               \
    const int kkp = (S) >> 1;                                                     \
    const int dyp = kkp / 3, dxp = kkp % 3;                                       \
    _Pragma("unroll")                                                             \
    for (int i = 0; i < 8; ++i) {                                                 \
      const int off = (((i >> 2) + dyp) * HALO_COLS + (i & 3) * 16 + dxp) * LDXC  \
                      + ((S) & 1) * 32;                                           \
      Aa[SLOT][i] = *reinterpret_cast<const short8*>(&Xs[(ln15 + off) * 1 + xbase \
                      + off - off + (ln15 * 0) + ((((i >> 2) + dyp) * HALO_COLS + (i & 3) * 16 + dxp + ln15) * LDXC + ((S) & 1) * 32 + xbase) - (ln15 + off + xbase)]); \
    }                                                                             \
  }
#undef LOADA
#define LOADA(SLOT, S)                                                            \
  {                                                                               \
    const int kkp = (S) >> 1;                                                     \
    const int dyp = kkp / 3, dxp = kkp % 3;                                       \
    _Pragma("unroll")                                                             \
    for (int i = 0; i < 8; ++i) {                                                 \
      const int pix = ((i >> 2) + dyp) * HALO_COLS + (i & 3) * 16 + ln15 + dxp;   \
      Aa[SLOT][i] = *reinterpret_cast<const short8*>(&Xs[pix * LDXC + ((S) & 1) * 32 + xbase]); \
    }                                                                             \
  }

  // ---- B prologue loads FIRST: L2 latency overlaps halo staging ----
  LOADB(0, 0)
  LOADB(1, 1)

  // ---- branch-mask codes: direct to registers (precomputed in prep) ----
  unsigned int cd[8];
  {
    const unsigned int* cp = codesg + (n << 12) + h0 * 64 + ln15;
#pragma unroll
    for (int i = 0; i < 8; ++i) cd[i] = cp[i * 16];
  }

  // ---- stage halo tile ONCE: Xs[(hrel*66 + ww+1)][c] = xt[n, h0-1+hrel, ww, c] ----
#pragma unroll
  for (int it = 0; it < 17; ++it) {
    const int idx = tid + it * 256;          // chunks of 8 channels
    if (idx < HALO_ROWS * HALO_COLS * 16) {
      const int ch = (idx & 15) << 3;
      const int pixidx = idx >> 4;           // 0..263
      const int lc = pixidx % HALO_COLS;
      const int hrel = pixidx / HALO_COLS;
      const int hh = h0 - 1 + hrel;
      const int ww = lc - 1;
      short8 v = {0, 0, 0, 0, 0, 0, 0, 0};
      if (hh >= 0 && hh < Hh && ww >= 0 && ww < Ww)
        v = *reinterpret_cast<const short8*>(
            xt + (size_t)((n * Hh + hh) * Ww + ww) * Cc + ch);
      *reinterpret_cast<short8*>(&Xs[pixidx * LDXC + ch]) = v;
    }
  }

  __syncthreads();

  const floatx4 zf4 = {0.f, 0.f, 0.f, 0.f};
  floatx4 acc[8][2];
#pragma unroll
  for (int i = 0; i < 8; ++i)
#pragma unroll
    for (int j = 0; j < 2; ++j) acc[i][j] = zf4;

  LOADA(0, 0)

  // ---- 18-step unrolled pipeline (wave tile M128 x N32 over K/2) ----
  // per step: 6 B VMEM (prefetch dist 2), 8 A ds_reads (dist 1), 48 MFMA.
#pragma unroll
  for (int s = 0; s < NSTEP; ++s) {
    if (s + 2 < NSTEP) LOADB((s + 2) % 3, s + 2)
    if (s + 1 < NSTEP) LOADA((s + 1) & 1, s + 1)
    const int kk = s >> 1;
    const int shift = 3 * kk;
    const short8* B = Bb[s % 3];
    const short8* A = Aa[s & 1];
#pragma unroll
    for (int b = 0; b < 3; ++b) {
#pragma unroll
      for (int i = 0; i < 8; ++i) {
        const int msk = __builtin_amdgcn_sbfe((int)cd[i], shift + b, 1);
        intx4 a4 = *reinterpret_cast<const intx4*>(&A[i]);
        intx4 m4 = {msk, msk, msk, msk};
        a4 &= m4;
        const short8 af = *reinterpret_cast<const short8*>(&a4);
        acc[i][0] = __builtin_amdgcn_mfma_f32_16x16x32_bf16(af, B[b * 2 + 0], acc[i][0], 0, 0, 0);
        acc[i][1] = __builtin_amdgcn_mfma_f32_16x16x32_bf16(af, B[b * 2 + 1], acc[i][1], 0, 0, 0);
      }
    }
    // schedule template: interleave VMEM/DS with MFMA (VALU unconstrained)
    SGB(0x020, 1, 0); SGB(0x008, 4, 0); SGB(0x100, 1, 0); SGB(0x008, 4, 0);
    SGB(0x020, 1, 0); SGB(0x008, 4, 0); SGB(0x100, 1, 0); SGB(0x008, 4, 0);
    SGB(0x020, 1, 0); SGB(0x008, 4, 0); SGB(0x100, 1, 0); SGB(0x008, 4, 0);
    SGB(0x020, 1, 0); SGB(0x008, 4, 0); SGB(0x100, 1, 0); SGB(0x008, 4, 0);
    SGB(0x020, 1, 0); SGB(0x008, 4, 0); SGB(0x100, 1, 0); SGB(0x008, 4, 0);
    SGB(0x020, 1, 0); SGB(0x008, 4, 0); SGB(0x100, 3, 0); SGB(0x008, 4, 0);
  }

  // ---- split-K reduction: ks=1 waves dump partials into LDS (Xs is dead) ----
  __syncthreads();
  float* scratch = reinterpret_cast<float*>(Xs);   // 32 KB used of 69.7 KB
  if (ks == 1) {
#pragma unroll
    for (int i = 0; i < 8; ++i)
#pragma unroll
      for (int j = 0; j < 2; ++j) {
        const int tile = (wc * 16 + i * 2 + j) * 64 + lane;
        *reinterpret_cast<floatx4*>(&scratch[tile * 4]) = acc[i][j];
      }
  }
  __syncthreads();
  if (ks == 0) {
#pragma unroll
    for (int i = 0; i < 8; ++i) {
      const int m = i * 16 + quad * 4;
      const int h = h0 + (m >> 6);
      const int w = m & 63;
#pragma unroll
      for (int j = 0; j < 2; ++j) {
        const int tile = (wc * 16 + i * 2 + j) * 64 + lane;
        const floatx4 other = *reinterpret_cast<const floatx4*>(&scratch[tile * 4]);
        const floatx4 sum = acc[i][j] + other;
        const int o = ob1 * 64 + wc * 32 + j * 16 + ln15;
        float* dst = out + (size_t)(n * Oo + o) * LL + h * Ww + w;
        *reinterpret_cast<floatx4*>(dst) = sum;
      }
    }
  }
}

extern "C" void kernel_launch(void* const* d_in, const int* in_sizes, int n_in,
                              void* d_out, int out_size, void* d_ws, size_t ws_size,
                              hipStream_t stream) {
  const float* x     = (const float*)d_in[0];
  const float* depth = (const float*)d_in[1];
  const float* fx    = (const float*)d_in[2];
  const float* w0    = (const float*)d_in[3];
  const float* w1    = (const float*)d_in[4];
  const float* w2    = (const float*)d_in[5];
  float* out = (float*)d_out;

  // ws layout: xt (8 MB) | wt2 (0.88 MB) | codes (128 KB)
  unsigned short* xt = (unsigned short*)d_ws;
  unsigned short* wt2 = xt + (size_t)Nn * Hh * Ww * Cc;
  unsigned int* codesg = (unsigned int*)(wt2 + (size_t)3 * KP * Oo * Cc);

  prep_all<<<Nn * Hh + 3 * Oo + 128, 256, 0, stream>>>(x, w0, w1, w2, depth, fx, xt, wt2, codesg);
  conv_main<<<512, 256, 0, stream>>>(xt, wt2, codesg, out);
}